// Round 18
// baseline (52.673 us; speedup 1.0000x reference)
//
#include <hip/hip_runtime.h>
#include <hip/hip_bf16.h>

#define EPSF 1e-5f

namespace {
constexpr int B = 64, D = 20000, C = 16, H = 64, EH = 128, L = 32;
constexpr int DPAD = ((D + 63) / 64) * 64;      // 20032
constexpr int NB = 640;                         // 2560 waves; ~4 units/wave
constexpr int UST = NB * 4;                     // 2560 (pair stride)
constexpr int JST = 2 * UST;                    // 5120 (loop stride)
constexpr int FB = 14;
constexpr int MAXU = B * (DPAD / 64);
}

typedef __attribute__((ext_vector_type(8))) short bf16x8;
typedef __attribute__((ext_vector_type(4))) float f32x4;
typedef __attribute__((ext_vector_type(2))) float f32x2;
typedef __attribute__((ext_vector_type(4))) unsigned int u32x4;

#if defined(__has_builtin)
#if __has_builtin(__builtin_amdgcn_permlane16_swap) && __has_builtin(__builtin_amdgcn_permlane32_swap)
#define HAVE_PL_SWAP 1
#endif
#endif
#ifndef HAVE_PL_SWAP
#define HAVE_PL_SWAP 0
#endif

static __device__ __forceinline__ unsigned short f2bf(float f) {
    __hip_bfloat16 h = __float2bfloat16(f);
    return __builtin_bit_cast(unsigned short, h);
}
static __device__ __forceinline__ unsigned int packbf(float lo, float hi) {
    return ((unsigned int)f2bf(hi) << 16) | (unsigned int)f2bf(lo);
}
static __device__ __forceinline__ unsigned int cvtpk(float lo, float hi) {
    __hip_bfloat162 h2 = __float22bfloat162_rn(make_float2(lo, hi));
    return ((unsigned int)__builtin_bit_cast(unsigned short, h2.y) << 16)
         | (unsigned int)__builtin_bit_cast(unsigned short, h2.x);
}
static __device__ __forceinline__ f32x2 pk_fma(f32x2 a, f32x2 b, f32x2 c) {
    return __builtin_elementwise_fma(a, b, c);
}
static __device__ __forceinline__ f32x2 pk_add(f32x2 a, f32x2 b) { return a + b; }
static __device__ __forceinline__ f32x2 pk_mul(f32x2 a, f32x2 b) { return a * b; }

// VALU-speed cross-lane partner fetch (round-17 polarity, verified passing)
static __device__ __forceinline__ float xadd16(float v) {
#if HAVE_PL_SWAP
    const int lane = threadIdx.x & 63;
    unsigned a = __builtin_bit_cast(unsigned, v);
    auto r = __builtin_amdgcn_permlane16_swap(a, a, false, false);
    unsigned p = (lane & 16) ? r[0] : r[1];
    return v + __builtin_bit_cast(float, p);
#else
    return v + __shfl_xor(v, 16);
#endif
}
static __device__ __forceinline__ float xadd32(float v) {
#if HAVE_PL_SWAP
    const int lane = threadIdx.x & 63;
    unsigned a = __builtin_bit_cast(unsigned, v);
    auto r = __builtin_amdgcn_permlane32_swap(a, a, false, false);
    unsigned p = (lane & 32) ? r[0] : r[1];
    return v + __builtin_bit_cast(float, p);
#else
    return v + __shfl_xor(v, 32);
#endif
}

// ---------- K1: single-pass compaction + prep (known-good) ----------
__global__ __launch_bounds__(1024) void k_prep(
    const int* __restrict__ mask, const float* __restrict__ x,
    const float* __restrict__ fe,
    const float* __restrict__ W1, const float* __restrict__ b1,
    const float* __restrict__ W2,
    int* __restrict__ cnt,
    unsigned short* __restrict__ cd, unsigned int* __restrict__ hxp,
    unsigned short* __restrict__ febf,
    unsigned short* __restrict__ W1T, unsigned short* __restrict__ W2T)
{
    const int t = threadIdx.x;
    if (blockIdx.x < B) {
        const int b = blockIdx.x;
        const size_t bD = (size_t)b * D;
        const size_t bP = (size_t)b * DPAD;
        constexpr int NIT = (D + 1023) / 1024;   // 20
        int   mv[NIT];
        float xv[NIT];
        #pragma unroll
        for (int it = 0; it < NIT; ++it) {
            const int d = it * 1024 + t;
            const bool in = d < D;
            mv[it] = in ? mask[bD + d] : 0;
            xv[it] = in ? x[bD + d] : 0.f;
        }
        int cl = 0;
        #pragma unroll
        for (int it = 0; it < NIT; ++it) cl += (mv[it] != 0) ? 1 : 0;

        const int lane = t & 63, wid = t >> 6;
        int inc = cl;
        #pragma unroll
        for (int off = 1; off < 64; off <<= 1) {
            const int v = __shfl_up(inc, off);
            if (lane >= off) inc += v;
        }
        __shared__ int ls[16];
        if (lane == 63) ls[wid] = inc;
        __syncthreads();
        int wbase = 0, tot = 0;
        #pragma unroll
        for (int k = 0; k < 16; ++k) {
            const int v = ls[k];
            tot += v;
            if (k < wid) wbase += v;
        }
        int pos = wbase + (inc - cl);

        #pragma unroll
        for (int it = 0; it < NIT; ++it) {
            if (mv[it]) {
                cd[bP + pos]  = (unsigned short)(it * 1024 + t);
                hxp[bP + pos] = packbf(xv[it], 1.0f);
                ++pos;
            }
        }
        const int padend = (tot + 63) & ~63;
        for (int i = tot + t; i < padend; i += 1024) {
            cd[bP + i] = 0;
            hxp[bP + i] = 0u;
        }
        if (t == 0) cnt[b] = tot;
    } else if (blockIdx.x == B) {
        // W1T permuted row->h so layer1 D-layout == layer2 B-layout
        for (int e = t; e < H * 32; e += 1024) {
            const int rIdx = e >> 5, kk = e & 31;
            const int m = rIdx >> 4, rho = rIdx & 15;
            const int h = 32 * (m >> 1) + 8 * (rho >> 2) + 4 * (m & 1) + (rho & 3);
            float v = 0.f;
            if (kk < 16)       v = W1[(kk + 1) * H + h];
            else if (kk == 16) v = W1[h];
            else if (kk == 17) v = b1[h];
            W1T[e] = f2bf(v);
        }
    } else if (blockIdx.x == B + 1) {
        for (int e = t; e < C * H; e += 1024) {
            const int c0 = e >> 6, hh = e & 63;
            W2T[e] = f2bf(W2[hh * C + c0]);
        }
    } else {
        const int pb = blockIdx.x - (B + 2);
        for (int u = pb * 1024 + t; u < (D * C) / 8; u += FB * 1024) {
            const float4 f0 = *(const float4*)(fe + (size_t)u * 8);
            const float4 f1 = *(const float4*)(fe + (size_t)u * 8 + 4);
            uint4 pk;
            pk.x = packbf(f0.x, f0.y); pk.y = packbf(f0.z, f0.w);
            pk.z = packbf(f1.x, f1.y); pk.w = packbf(f1.z, f1.w);
            *(uint4*)(febf + (size_t)u * 8) = pk;
        }
    }
}

// ---- per-iteration unit body (round-17, passing) ----
static __device__ __forceinline__ void unit_it(
    const bf16x8& hbv, int rem, int pq,
    const bf16x8 (&w1f)[4], const bf16x8 (&w2f)[2],
    const f32x2 (&g1p)[4][2], const f32x2 (&be1p)[4][2],
    const f32x2& g2lo, const f32x2& g2hi,
    const f32x2& be2lo, const f32x2& be2hi,
    const f32x2& b2lo, const f32x2& b2hi,
    f32x2& laccLo, f32x2& laccHi)
{
    const f32x4 z = {0.f, 0.f, 0.f, 0.f};
    f32x4 t1a[4];
    #pragma unroll
    for (int m = 0; m < 4; ++m)
        t1a[m] = __builtin_amdgcn_mfma_f32_16x16x32_bf16(w1f[m], hbv, z, 0, 0, 0);

    f32x2 sp = {0.f, 0.f}, qp = {0.f, 0.f};
    f32x2 tl[4], th[4];
    #pragma unroll
    for (int m = 0; m < 4; ++m) {
        tl[m] = __builtin_shufflevector(t1a[m], t1a[m], 0, 1);
        th[m] = __builtin_shufflevector(t1a[m], t1a[m], 2, 3);
        sp = pk_add(sp, pk_add(tl[m], th[m]));
        qp = pk_fma(tl[m], tl[m], pk_fma(th[m], th[m], qp));
    }
    float s  = sp[0] + sp[1];
    float sq = qp[0] + qp[1];
    s = xadd16(s);  sq = xadd16(sq);
    s = xadd32(s);  sq = xadd32(sq);
    const float mean1 = s * (1.f / H);
    const float var1  = fmaxf(sq * (1.f / H) - mean1 * mean1, 0.f);
    const float rstd1 = rsqrtf(var1 + EPSF);

    const f32x2 rr2 = {rstd1, rstd1};
    const f32x2 nm2 = {-mean1, -mean1};
    unsigned int pw[8];
    #pragma unroll
    for (int m = 0; m < 4; ++m) {
        const f32x2 sgl = pk_mul(g1p[m][0], rr2);
        const f32x2 sgh = pk_mul(g1p[m][1], rr2);
        const f32x2 obl = pk_fma(sgl, nm2, be1p[m][0]);
        const f32x2 obh = pk_fma(sgh, nm2, be1p[m][1]);
        const f32x2 yl = pk_fma(tl[m], sgl, obl);
        const f32x2 yh = pk_fma(th[m], sgh, obh);
        pw[2 * m]     = cvtpk(fmaxf(yl[0], 0.f), fmaxf(yl[1], 0.f));
        pw[2 * m + 1] = cvtpk(fmaxf(yh[0], 0.f), fmaxf(yh[1], 0.f));
    }
    const u32x4 r0 = {pw[0], pw[1], pw[2], pw[3]};
    const u32x4 r1 = {pw[4], pw[5], pw[6], pw[7]};
    const bf16x8 rb0 = __builtin_bit_cast(bf16x8, r0);
    const bf16x8 rb1 = __builtin_bit_cast(bf16x8, r1);

    f32x4 a2 = __builtin_amdgcn_mfma_f32_16x16x32_bf16(w2f[0], rb0, z, 0, 0, 0);
    a2 = __builtin_amdgcn_mfma_f32_16x16x32_bf16(w2f[1], rb1, a2, 0, 0, 0);

    f32x2 alo = __builtin_shufflevector(a2, a2, 0, 1);
    f32x2 ahi = __builtin_shufflevector(a2, a2, 2, 3);
    alo = pk_add(alo, b2lo);
    ahi = pk_add(ahi, b2hi);
    const f32x2 sp2 = pk_add(alo, ahi);
    const f32x2 zz = {0.f, 0.f};
    const f32x2 qp2 = pk_fma(alo, alo, pk_fma(ahi, ahi, zz));
    float s2 = sp2[0] + sp2[1];
    float q2 = qp2[0] + qp2[1];
    s2 = xadd16(s2);  q2 = xadd16(q2);
    s2 = xadd32(s2);  q2 = xadd32(q2);
    const float mean2 = s2 * (1.f / C);
    const float var2  = fmaxf(q2 * (1.f / C) - mean2 * mean2, 0.f);
    const float rstd2 = rsqrtf(var2 + EPSF);

    const f32x2 rrb = {rstd2, rstd2};
    const f32x2 nmb = {-mean2, -mean2};
    const f32x2 sg2l = pk_mul(g2lo, rrb);
    const f32x2 sg2h = pk_mul(g2hi, rrb);
    const f32x2 ob2l = pk_fma(sg2l, nmb, be2lo);
    const f32x2 ob2h = pk_fma(sg2h, nmb, be2hi);
    const f32x2 y2l = pk_fma(alo, sg2l, ob2l);
    const f32x2 y2h = pk_fma(ahi, sg2h, ob2h);
    const float vm = (pq < rem) ? 1.f : 0.f;
    const f32x2 vm2 = {vm, vm};
    const f32x2 rl = {fmaxf(y2l[0], 0.f), fmaxf(y2l[1], 0.f)};
    const f32x2 rh = {fmaxf(y2h[0], 0.f), fmaxf(y2h[1], 0.f)};
    laccLo = pk_fma(rl, vm2, laccLo);
    laccHi = pk_fma(rh, vm2, laccHi);
}

// ---------- K2: MFMA pointnet, ~4 units per wave (looped pair body) ----------
__global__ __launch_bounds__(256, 2) void k_rows(
    const int* __restrict__ cnt,
    const unsigned short* __restrict__ cd, const unsigned int* __restrict__ hxp,
    const unsigned short* __restrict__ febf,
    const unsigned short* __restrict__ W1T, const unsigned short* __restrict__ W2T,
    const float* __restrict__ g1, const float* __restrict__ be1,
    const float* __restrict__ g2, const float* __restrict__ be2,
    const float* __restrict__ b2,
    float* __restrict__ part)      // [MAXU][C]
{
    const int tid = threadIdx.x;
    const int w = tid >> 6, lane = tid & 63;
    const int g = lane >> 4, q = lane & 15;

    const int cv  = cnt[lane];
    const int nuv = (cv + 63) >> 6;
    int Pi = nuv;
    #pragma unroll
    for (int off = 1; off < 64; off <<= 1) {
        const int pv = __shfl_up(Pi, off);
        if (lane >= off) Pi += pv;
    }
    const int T = __shfl(Pi, 63);

    const int gw = blockIdx.x * 4 + w;           // 0..2559
    if (gw >= T) return;

    bf16x8 w1f[4];
    #pragma unroll
    for (int m = 0; m < 4; ++m)
        w1f[m] = *(const bf16x8*)(W1T + (16 * m + q) * 32 + 8 * g);
    bf16x8 w2f[2];
    #pragma unroll
    for (int ks = 0; ks < 2; ++ks)
        w2f[ks] = *(const bf16x8*)(W2T + q * 64 + 32 * ks + 8 * g);

    f32x2 g1p[4][2], be1p[4][2];
    #pragma unroll
    for (int m = 0; m < 4; ++m) {
        const int h0 = 32 * (m >> 1) + 8 * g + 4 * (m & 1);
        g1p[m][0]  = *(const f32x2*)(g1  + h0);
        g1p[m][1]  = *(const f32x2*)(g1  + h0 + 2);
        be1p[m][0] = *(const f32x2*)(be1 + h0);
        be1p[m][1] = *(const f32x2*)(be1 + h0 + 2);
    }
    const f32x2 g2lo  = *(const f32x2*)(g2  + 4 * g);
    const f32x2 g2hi  = *(const f32x2*)(g2  + 4 * g + 2);
    const f32x2 be2lo = *(const f32x2*)(be2 + 4 * g);
    const f32x2 be2hi = *(const f32x2*)(be2 + 4 * g + 2);
    const f32x2 b2lo  = *(const f32x2*)(b2  + 4 * g);
    const f32x2 b2hi  = *(const f32x2*)(b2  + 4 * g + 2);

    for (int uA = gw; uA < T; uA += JST) {
        const bool hasB = (uA + UST) < T;
        const int uB = hasB ? uA + UST : uA;

        // resolve both units: unit -> (batch row base, remaining valid points)
        size_t rowbA, rowbB;
        int remA, remB;
        {
            const unsigned long long blA = __ballot(Pi <= uA);
            const int bA   = __popcll(blA);
            const int PbA  = __shfl(Pi, bA);
            const int nubA = __shfl(nuv, bA);
            const int nA   = __shfl(cv, bA);
            const int baseA = (uA - (PbA - nubA)) * 64;
            rowbA = (size_t)bA * DPAD + baseA;
            remA  = nA - baseA;
            const unsigned long long blB = __ballot(Pi <= uB);
            const int bB   = __popcll(blB);
            const int PbB  = __shfl(Pi, bB);
            const int nubB = __shfl(nuv, bB);
            const int nB   = __shfl(cv, bB);
            const int baseB = (uB - (PbB - nubB)) * 64;
            rowbB = (size_t)bB * DPAD + baseB;
            remB  = nB - baseB;
        }

        const int dvA = (int)cd[rowbA + lane];
        const int dvB = (int)cd[rowbB + lane];

        bf16x8 hbA[4], hbB[4];
        #pragma unroll
        for (int it = 0; it < 4; ++it) {
            const int p = (it << 4) + q;
            {
                const int dd = __shfl(dvA, p);
                bf16x8 hv = {0, 0, 0, 0, 0, 0, 0, 0};
                if (g < 2) {
                    hv = *(const bf16x8*)(febf + (size_t)dd * 16 + 8 * g);
                } else if (g == 2) {
                    const unsigned int xv = hxp[rowbA + p];
                    const u32x4 tmp = {xv, 0u, 0u, 0u};
                    hv = __builtin_bit_cast(bf16x8, tmp);
                }
                hbA[it] = hv;
            }
            {
                const int dd = __shfl(dvB, p);
                bf16x8 hv = {0, 0, 0, 0, 0, 0, 0, 0};
                if (g < 2) {
                    hv = *(const bf16x8*)(febf + (size_t)dd * 16 + 8 * g);
                } else if (g == 2) {
                    const unsigned int xv = hxp[rowbB + p];
                    const u32x4 tmp = {xv, 0u, 0u, 0u};
                    hv = __builtin_bit_cast(bf16x8, tmp);
                }
                hbB[it] = hv;
            }
        }

        f32x2 laLoA = {0.f, 0.f}, laHiA = {0.f, 0.f};
        f32x2 laLoB = {0.f, 0.f}, laHiB = {0.f, 0.f};
        #pragma unroll
        for (int it = 0; it < 4; ++it) {
            const int pq = (it << 4) + q;
            unit_it(hbA[it], remA, pq, w1f, w2f, g1p, be1p,
                    g2lo, g2hi, be2lo, be2hi, b2lo, b2hi, laLoA, laHiA);
            unit_it(hbB[it], remB, pq, w1f, w2f, g1p, be1p,
                    g2lo, g2hi, be2lo, be2hi, b2lo, b2hi, laLoB, laHiB);
        }

        // pool over the 16 point-columns; lane (g, q==0) writes c = 4g..4g+3
        float a0 = laLoA[0], a1 = laLoA[1], a2 = laHiA[0], a3 = laHiA[1];
        float b0 = laLoB[0], b1 = laLoB[1], b2v_ = laHiB[0], b3 = laHiB[1];
        #pragma unroll
        for (int off = 1; off < 16; off <<= 1) {
            a0 += __shfl_xor(a0, off);  a1 += __shfl_xor(a1, off);
            a2 += __shfl_xor(a2, off);  a3 += __shfl_xor(a3, off);
            b0 += __shfl_xor(b0, off);  b1 += __shfl_xor(b1, off);
            b2v_ += __shfl_xor(b2v_, off);  b3 += __shfl_xor(b3, off);
        }
        if (q == 0) {
            *(float4*)(part + (size_t)uA * C + 4 * g) = make_float4(a0, a1, a2, a3);
            if (hasB)
                *(float4*)(part + (size_t)uB * C + 4 * g) = make_float4(b0, b1, b2v_, b3);
        }
    }
}

// ---------- K3: encoder MLP per batch (unchanged) ----------
__global__ __launch_bounds__(EH) void k_enc(
    const float* __restrict__ part, const int* __restrict__ cnt,
    const float* __restrict__ We1, const float* __restrict__ bb1,
    const float* __restrict__ gg1, const float* __restrict__ bbe1,
    const float* __restrict__ We2, const float* __restrict__ bb2,
    const float* __restrict__ gg2, const float* __restrict__ bbe2,
    float* __restrict__ out)
{
    const int b = blockIdx.x;
    const int t = threadIdx.x;
    __shared__ int sP[64];
    __shared__ float red[8][16];
    __shared__ float cc[C];
    __shared__ float stats[2];
    __shared__ float buf[EH];
    __shared__ float buf2[2 * L];

    if (t < 64) {
        int p = (cnt[t] + 63) >> 6;
        #pragma unroll
        for (int off = 1; off < 64; off <<= 1) {
            const int pv = __shfl_up(p, off);
            if (t >= off) p += pv;
        }
        sP[t] = p;
    }
    __syncthreads();
    const int n = cnt[b];
    const int row0 = (b == 0) ? 0 : sP[b - 1];
    const int rows = sP[b] - row0;

    {
        const int c = t & 15, s = t >> 4;
        float ps = 0.f;
        for (int r = s; r < rows; r += 8)
            ps += part[(size_t)(row0 + r) * C + c];
        red[s][c] = ps;
    }
    __syncthreads();
    if (t < C) {
        float v = 0.f;
        #pragma unroll
        for (int s = 0; s < 8; ++s) v += red[s][t];
        cc[t] = v;
    }
    __syncthreads();
    const float inv = 1.f / fmaxf((float)n, 1.f);

    float v1 = bb1[t];
    #pragma unroll
    for (int c = 0; c < C; ++c)
        v1 = fmaf(cc[c] * inv, We1[c * EH + t], v1);
    buf[t] = v1;
    __syncthreads();
    if (t == 0) {
        float s = 0.f, ss = 0.f;
        for (int j2 = 0; j2 < EH; ++j2) { s += buf[j2]; ss = fmaf(buf[j2], buf[j2], ss); }
        float mn = s * (1.f / EH);
        float vr = fmaxf(ss * (1.f / EH) - mn * mn, 0.f);
        stats[0] = mn; stats[1] = rsqrtf(vr + EPSF);
    }
    __syncthreads();
    float e1 = fmaxf(fmaf((v1 - stats[0]) * stats[1], gg1[t], bbe1[t]), 0.f);
    __syncthreads();
    buf[t] = e1;
    __syncthreads();

    float v2 = 0.f;
    if (t < 2 * L) {
        v2 = bb2[t];
        #pragma unroll
        for (int h = 0; h < EH; ++h)
            v2 = fmaf(buf[h], We2[h * (2 * L) + t], v2);
        buf2[t] = v2;
    }
    __syncthreads();
    if (t == 0) {
        float s = 0.f, ss = 0.f;
        for (int j2 = 0; j2 < 2 * L; ++j2) { s += buf2[j2]; ss = fmaf(buf2[j2], buf2[j2], ss); }
        float mn = s * (1.f / (2 * L));
        float vr = fmaxf(ss * (1.f / (2 * L)) - mn * mn, 0.f);
        stats[0] = mn; stats[1] = rsqrtf(vr + EPSF);
    }
    __syncthreads();
    if (t < 2 * L) {
        float e2 = fmaxf(fmaf((v2 - stats[0]) * stats[1], gg2[t], bbe2[t]), 0.f);
        if (t < L) out[(size_t)b * L + t]                       = e2;  // mu
        else       out[(size_t)B * L + (size_t)b * L + (t - L)] = e2;  // logvar
    }
}

extern "C" void kernel_launch(void* const* d_in, const int* in_sizes, int n_in,
                              void* d_out, int out_size, void* d_ws, size_t ws_size,
                              hipStream_t stream) {
    const float* x    = (const float*)d_in[0];
    const int*   mask = (const int*)d_in[1];
    const float* fe   = (const float*)d_in[2];
    const float* W1   = (const float*)d_in[3];
    const float* b1   = (const float*)d_in[4];
    const float* g1   = (const float*)d_in[5];
    const float* be1  = (const float*)d_in[6];
    const float* W2   = (const float*)d_in[7];
    const float* b2   = (const float*)d_in[8];
    const float* g2   = (const float*)d_in[9];
    const float* be2  = (const float*)d_in[10];
    const float* We1  = (const float*)d_in[11];
    const float* bb1  = (const float*)d_in[12];
    const float* gg1  = (const float*)d_in[13];
    const float* bbe1 = (const float*)d_in[14];
    const float* We2  = (const float*)d_in[15];
    const float* bb2  = (const float*)d_in[16];
    const float* gg2  = (const float*)d_in[17];
    const float* bbe2 = (const float*)d_in[18];
    float* out = (float*)d_out;

    char* wp = (char*)d_ws;
    float* part     = (float*)wp;               wp += (size_t)MAXU * C * 4;
    int*   cnt      = (int*)wp;                 wp += (size_t)B * 4;
    unsigned short* W1T = (unsigned short*)wp;  wp += (size_t)H * 32 * 2;
    unsigned short* W2T = (unsigned short*)wp;  wp += (size_t)C * H * 2;
    unsigned short* febf = (unsigned short*)wp; wp += (size_t)D * C * 2;
    unsigned int*   hxp = (unsigned int*)wp;    wp += (size_t)B * DPAD * 4;
    unsigned short* cd  = (unsigned short*)wp;

    hipLaunchKernelGGL(k_prep, dim3(B + 2 + FB), dim3(1024), 0, stream,
                       mask, x, fe, W1, b1, W2, cnt, cd, hxp, febf, W1T, W2T);
    hipLaunchKernelGGL(k_rows, dim3(NB), dim3(256), 0, stream,
                       cnt, cd, hxp, febf, W1T, W2T, g1, be1, g2, be2, b2, part);
    hipLaunchKernelGGL(k_enc, dim3(B), dim3(EH), 0, stream,
                       part, cnt, We1, bb1, gg1, bbe1, We2, bb2, gg2, bbe2, out);
}

// Round 19
// 49.218 us; speedup vs baseline: 1.0702x; 1.0702x over previous
//
#include <hip/hip_runtime.h>
#include <hip/hip_bf16.h>

#define EPSF 1e-5f

namespace {
constexpr int B = 64, D = 20000, C = 16, H = 64, EH = 128, L = 32;
constexpr int DPAD = ((D + 63) / 64) * 64;      // 20032
constexpr int NW = 5120;                        // 1-wave blocks; 2 units/wave
constexpr int SSTRIDE = NW;                     // pair partner stride
constexpr int FB = 14;
constexpr int MAXU = B * (DPAD / 64);
}

typedef __attribute__((ext_vector_type(8))) short bf16x8;
typedef __attribute__((ext_vector_type(4))) float f32x4;
typedef __attribute__((ext_vector_type(2))) float f32x2;
typedef __attribute__((ext_vector_type(4))) unsigned int u32x4;

#if defined(__has_builtin)
#if __has_builtin(__builtin_amdgcn_permlane16_swap) && __has_builtin(__builtin_amdgcn_permlane32_swap)
#define HAVE_PL_SWAP 1
#endif
#endif
#ifndef HAVE_PL_SWAP
#define HAVE_PL_SWAP 0
#endif

static __device__ __forceinline__ unsigned short f2bf(float f) {
    __hip_bfloat16 h = __float2bfloat16(f);
    return __builtin_bit_cast(unsigned short, h);
}
static __device__ __forceinline__ unsigned int packbf(float lo, float hi) {
    return ((unsigned int)f2bf(hi) << 16) | (unsigned int)f2bf(lo);
}
static __device__ __forceinline__ unsigned int cvtpk(float lo, float hi) {
    __hip_bfloat162 h2 = __float22bfloat162_rn(make_float2(lo, hi));
    return ((unsigned int)__builtin_bit_cast(unsigned short, h2.y) << 16)
         | (unsigned int)__builtin_bit_cast(unsigned short, h2.x);
}
static __device__ __forceinline__ f32x2 pk_fma(f32x2 a, f32x2 b, f32x2 c) {
    return __builtin_elementwise_fma(a, b, c);
}
static __device__ __forceinline__ f32x2 pk_add(f32x2 a, f32x2 b) { return a + b; }
static __device__ __forceinline__ f32x2 pk_mul(f32x2 a, f32x2 b) { return a * b; }

// VALU-speed cross-lane partner fetch (round-17 polarity, verified passing)
static __device__ __forceinline__ float xadd16(float v) {
#if HAVE_PL_SWAP
    const int lane = threadIdx.x & 63;
    unsigned a = __builtin_bit_cast(unsigned, v);
    auto r = __builtin_amdgcn_permlane16_swap(a, a, false, false);
    unsigned p = (lane & 16) ? r[0] : r[1];
    return v + __builtin_bit_cast(float, p);
#else
    return v + __shfl_xor(v, 16);
#endif
}
static __device__ __forceinline__ float xadd32(float v) {
#if HAVE_PL_SWAP
    const int lane = threadIdx.x & 63;
    unsigned a = __builtin_bit_cast(unsigned, v);
    auto r = __builtin_amdgcn_permlane32_swap(a, a, false, false);
    unsigned p = (lane & 32) ? r[0] : r[1];
    return v + __builtin_bit_cast(float, p);
#else
    return v + __shfl_xor(v, 32);
#endif
}

// ---------- K1: single-pass compaction + prep (known-good) ----------
__global__ __launch_bounds__(1024) void k_prep(
    const int* __restrict__ mask, const float* __restrict__ x,
    const float* __restrict__ fe,
    const float* __restrict__ W1, const float* __restrict__ b1,
    const float* __restrict__ W2,
    int* __restrict__ cnt,
    unsigned short* __restrict__ cd, unsigned int* __restrict__ hxp,
    unsigned short* __restrict__ febf,
    unsigned short* __restrict__ W1T, unsigned short* __restrict__ W2T)
{
    const int t = threadIdx.x;
    if (blockIdx.x < B) {
        const int b = blockIdx.x;
        const size_t bD = (size_t)b * D;
        const size_t bP = (size_t)b * DPAD;
        constexpr int NIT = (D + 1023) / 1024;   // 20
        int   mv[NIT];
        float xv[NIT];
        #pragma unroll
        for (int it = 0; it < NIT; ++it) {
            const int d = it * 1024 + t;
            const bool in = d < D;
            mv[it] = in ? mask[bD + d] : 0;
            xv[it] = in ? x[bD + d] : 0.f;
        }
        int cl = 0;
        #pragma unroll
        for (int it = 0; it < NIT; ++it) cl += (mv[it] != 0) ? 1 : 0;

        const int lane = t & 63, wid = t >> 6;
        int inc = cl;
        #pragma unroll
        for (int off = 1; off < 64; off <<= 1) {
            const int v = __shfl_up(inc, off);
            if (lane >= off) inc += v;
        }
        __shared__ int ls[16];
        if (lane == 63) ls[wid] = inc;
        __syncthreads();
        int wbase = 0, tot = 0;
        #pragma unroll
        for (int k = 0; k < 16; ++k) {
            const int v = ls[k];
            tot += v;
            if (k < wid) wbase += v;
        }
        int pos = wbase + (inc - cl);

        #pragma unroll
        for (int it = 0; it < NIT; ++it) {
            if (mv[it]) {
                cd[bP + pos]  = (unsigned short)(it * 1024 + t);
                hxp[bP + pos] = packbf(xv[it], 1.0f);
                ++pos;
            }
        }
        const int padend = (tot + 63) & ~63;
        for (int i = tot + t; i < padend; i += 1024) {
            cd[bP + i] = 0;
            hxp[bP + i] = 0u;
        }
        if (t == 0) cnt[b] = tot;
    } else if (blockIdx.x == B) {
        // W1T permuted row->h so layer1 D-layout == layer2 B-layout
        for (int e = t; e < H * 32; e += 1024) {
            const int rIdx = e >> 5, kk = e & 31;
            const int m = rIdx >> 4, rho = rIdx & 15;
            const int h = 32 * (m >> 1) + 8 * (rho >> 2) + 4 * (m & 1) + (rho & 3);
            float v = 0.f;
            if (kk < 16)       v = W1[(kk + 1) * H + h];
            else if (kk == 16) v = W1[h];
            else if (kk == 17) v = b1[h];
            W1T[e] = f2bf(v);
        }
    } else if (blockIdx.x == B + 1) {
        for (int e = t; e < C * H; e += 1024) {
            const int c0 = e >> 6, hh = e & 63;
            W2T[e] = f2bf(W2[hh * C + c0]);
        }
    } else {
        const int pb = blockIdx.x - (B + 2);
        for (int u = pb * 1024 + t; u < (D * C) / 8; u += FB * 1024) {
            const float4 f0 = *(const float4*)(fe + (size_t)u * 8);
            const float4 f1 = *(const float4*)(fe + (size_t)u * 8 + 4);
            uint4 pk;
            pk.x = packbf(f0.x, f0.y); pk.y = packbf(f0.z, f0.w);
            pk.z = packbf(f1.x, f1.y); pk.w = packbf(f1.z, f1.w);
            *(uint4*)(febf + (size_t)u * 8) = pk;
        }
    }
}

// ---- per-iteration unit body (round-17, passing) ----
static __device__ __forceinline__ void unit_it(
    const bf16x8& hbv, int rem, int pq,
    const bf16x8 (&w1f)[4], const bf16x8 (&w2f)[2],
    const f32x2 (&g1p)[4][2], const f32x2 (&be1p)[4][2],
    const f32x2& g2lo, const f32x2& g2hi,
    const f32x2& be2lo, const f32x2& be2hi,
    const f32x2& b2lo, const f32x2& b2hi,
    f32x2& laccLo, f32x2& laccHi)
{
    const f32x4 z = {0.f, 0.f, 0.f, 0.f};
    f32x4 t1a[4];
    #pragma unroll
    for (int m = 0; m < 4; ++m)
        t1a[m] = __builtin_amdgcn_mfma_f32_16x16x32_bf16(w1f[m], hbv, z, 0, 0, 0);

    f32x2 sp = {0.f, 0.f}, qp = {0.f, 0.f};
    f32x2 tl[4], th[4];
    #pragma unroll
    for (int m = 0; m < 4; ++m) {
        tl[m] = __builtin_shufflevector(t1a[m], t1a[m], 0, 1);
        th[m] = __builtin_shufflevector(t1a[m], t1a[m], 2, 3);
        sp = pk_add(sp, pk_add(tl[m], th[m]));
        qp = pk_fma(tl[m], tl[m], pk_fma(th[m], th[m], qp));
    }
    float s  = sp[0] + sp[1];
    float sq = qp[0] + qp[1];
    s = xadd16(s);  sq = xadd16(sq);
    s = xadd32(s);  sq = xadd32(sq);
    const float mean1 = s * (1.f / H);
    const float var1  = fmaxf(sq * (1.f / H) - mean1 * mean1, 0.f);
    const float rstd1 = rsqrtf(var1 + EPSF);

    const f32x2 rr2 = {rstd1, rstd1};
    const f32x2 nm2 = {-mean1, -mean1};
    unsigned int pw[8];
    #pragma unroll
    for (int m = 0; m < 4; ++m) {
        const f32x2 sgl = pk_mul(g1p[m][0], rr2);
        const f32x2 sgh = pk_mul(g1p[m][1], rr2);
        const f32x2 obl = pk_fma(sgl, nm2, be1p[m][0]);
        const f32x2 obh = pk_fma(sgh, nm2, be1p[m][1]);
        const f32x2 yl = pk_fma(tl[m], sgl, obl);
        const f32x2 yh = pk_fma(th[m], sgh, obh);
        pw[2 * m]     = cvtpk(fmaxf(yl[0], 0.f), fmaxf(yl[1], 0.f));
        pw[2 * m + 1] = cvtpk(fmaxf(yh[0], 0.f), fmaxf(yh[1], 0.f));
    }
    const u32x4 r0 = {pw[0], pw[1], pw[2], pw[3]};
    const u32x4 r1 = {pw[4], pw[5], pw[6], pw[7]};
    const bf16x8 rb0 = __builtin_bit_cast(bf16x8, r0);
    const bf16x8 rb1 = __builtin_bit_cast(bf16x8, r1);

    f32x4 a2 = __builtin_amdgcn_mfma_f32_16x16x32_bf16(w2f[0], rb0, z, 0, 0, 0);
    a2 = __builtin_amdgcn_mfma_f32_16x16x32_bf16(w2f[1], rb1, a2, 0, 0, 0);

    f32x2 alo = __builtin_shufflevector(a2, a2, 0, 1);
    f32x2 ahi = __builtin_shufflevector(a2, a2, 2, 3);
    alo = pk_add(alo, b2lo);
    ahi = pk_add(ahi, b2hi);
    const f32x2 sp2 = pk_add(alo, ahi);
    const f32x2 zz = {0.f, 0.f};
    const f32x2 qp2 = pk_fma(alo, alo, pk_fma(ahi, ahi, zz));
    float s2 = sp2[0] + sp2[1];
    float q2 = qp2[0] + qp2[1];
    s2 = xadd16(s2);  q2 = xadd16(q2);
    s2 = xadd32(s2);  q2 = xadd32(q2);
    const float mean2 = s2 * (1.f / C);
    const float var2  = fmaxf(q2 * (1.f / C) - mean2 * mean2, 0.f);
    const float rstd2 = rsqrtf(var2 + EPSF);

    const f32x2 rrb = {rstd2, rstd2};
    const f32x2 nmb = {-mean2, -mean2};
    const f32x2 sg2l = pk_mul(g2lo, rrb);
    const f32x2 sg2h = pk_mul(g2hi, rrb);
    const f32x2 ob2l = pk_fma(sg2l, nmb, be2lo);
    const f32x2 ob2h = pk_fma(sg2h, nmb, be2hi);
    const f32x2 y2l = pk_fma(alo, sg2l, ob2l);
    const f32x2 y2h = pk_fma(ahi, sg2h, ob2h);
    const float vm = (pq < rem) ? 1.f : 0.f;
    const f32x2 vm2 = {vm, vm};
    const f32x2 rl = {fmaxf(y2l[0], 0.f), fmaxf(y2l[1], 0.f)};
    const f32x2 rh = {fmaxf(y2h[0], 0.f), fmaxf(y2h[1], 0.f)};
    laccLo = pk_fma(rl, vm2, laccLo);
    laccHi = pk_fma(rh, vm2, laccHi);
}

// ---------- K2: MFMA pointnet, 1-wave blocks (max CU wave-packing) ----------
__global__ __launch_bounds__(64, 4) void k_rows(
    const int* __restrict__ cnt,
    const unsigned short* __restrict__ cd, const unsigned int* __restrict__ hxp,
    const unsigned short* __restrict__ febf,
    const unsigned short* __restrict__ W1T, const unsigned short* __restrict__ W2T,
    const float* __restrict__ g1, const float* __restrict__ be1,
    const float* __restrict__ g2, const float* __restrict__ be2,
    const float* __restrict__ b2,
    float* __restrict__ part)      // [MAXU][C]
{
    const int lane = threadIdx.x & 63;
    const int g = lane >> 4, q = lane & 15;

    const int cv  = cnt[lane];
    const int nuv = (cv + 63) >> 6;
    int Pi = nuv;
    #pragma unroll
    for (int off = 1; off < 64; off <<= 1) {
        const int pv = __shfl_up(Pi, off);
        if (lane >= off) Pi += pv;
    }
    const int T = __shfl(Pi, 63);

    const int uA = blockIdx.x;
    if (uA >= T) return;
    const bool hasB = (uA + SSTRIDE) < T;
    const int uB = hasB ? uA + SSTRIDE : uA;

    bf16x8 w1f[4];
    #pragma unroll
    for (int m = 0; m < 4; ++m)
        w1f[m] = *(const bf16x8*)(W1T + (16 * m + q) * 32 + 8 * g);
    bf16x8 w2f[2];
    #pragma unroll
    for (int ks = 0; ks < 2; ++ks)
        w2f[ks] = *(const bf16x8*)(W2T + q * 64 + 32 * ks + 8 * g);

    f32x2 g1p[4][2], be1p[4][2];
    #pragma unroll
    for (int m = 0; m < 4; ++m) {
        const int h0 = 32 * (m >> 1) + 8 * g + 4 * (m & 1);
        g1p[m][0]  = *(const f32x2*)(g1  + h0);
        g1p[m][1]  = *(const f32x2*)(g1  + h0 + 2);
        be1p[m][0] = *(const f32x2*)(be1 + h0);
        be1p[m][1] = *(const f32x2*)(be1 + h0 + 2);
    }
    const f32x2 g2lo  = *(const f32x2*)(g2  + 4 * g);
    const f32x2 g2hi  = *(const f32x2*)(g2  + 4 * g + 2);
    const f32x2 be2lo = *(const f32x2*)(be2 + 4 * g);
    const f32x2 be2hi = *(const f32x2*)(be2 + 4 * g + 2);
    const f32x2 b2lo  = *(const f32x2*)(b2  + 4 * g);
    const f32x2 b2hi  = *(const f32x2*)(b2  + 4 * g + 2);

    // resolve both units: unit -> (batch row base, remaining valid points)
    size_t rowbA, rowbB;
    int remA, remB;
    {
        const unsigned long long blA = __ballot(Pi <= uA);
        const int bA   = __popcll(blA);
        const int PbA  = __shfl(Pi, bA);
        const int nubA = __shfl(nuv, bA);
        const int nA   = __shfl(cv, bA);
        const int baseA = (uA - (PbA - nubA)) * 64;
        rowbA = (size_t)bA * DPAD + baseA;
        remA  = nA - baseA;
        const unsigned long long blB = __ballot(Pi <= uB);
        const int bB   = __popcll(blB);
        const int PbB  = __shfl(Pi, bB);
        const int nubB = __shfl(nuv, bB);
        const int nB   = __shfl(cv, bB);
        const int baseB = (uB - (PbB - nubB)) * 64;
        rowbB = (size_t)bB * DPAD + baseB;
        remB  = nB - baseB;
    }

    const int dvA = (int)cd[rowbA + lane];
    const int dvB = (int)cd[rowbB + lane];

    bf16x8 hbA[4], hbB[4];
    #pragma unroll
    for (int it = 0; it < 4; ++it) {
        const int p = (it << 4) + q;
        {
            const int dd = __shfl(dvA, p);
            bf16x8 hv = {0, 0, 0, 0, 0, 0, 0, 0};
            if (g < 2) {
                hv = *(const bf16x8*)(febf + (size_t)dd * 16 + 8 * g);
            } else if (g == 2) {
                const unsigned int xv = hxp[rowbA + p];
                const u32x4 tmp = {xv, 0u, 0u, 0u};
                hv = __builtin_bit_cast(bf16x8, tmp);
            }
            hbA[it] = hv;
        }
        {
            const int dd = __shfl(dvB, p);
            bf16x8 hv = {0, 0, 0, 0, 0, 0, 0, 0};
            if (g < 2) {
                hv = *(const bf16x8*)(febf + (size_t)dd * 16 + 8 * g);
            } else if (g == 2) {
                const unsigned int xv = hxp[rowbB + p];
                const u32x4 tmp = {xv, 0u, 0u, 0u};
                hv = __builtin_bit_cast(bf16x8, tmp);
            }
            hbB[it] = hv;
        }
    }

    f32x2 laLoA = {0.f, 0.f}, laHiA = {0.f, 0.f};
    f32x2 laLoB = {0.f, 0.f}, laHiB = {0.f, 0.f};
    #pragma unroll
    for (int it = 0; it < 4; ++it) {
        const int pq = (it << 4) + q;
        unit_it(hbA[it], remA, pq, w1f, w2f, g1p, be1p,
                g2lo, g2hi, be2lo, be2hi, b2lo, b2hi, laLoA, laHiA);
        unit_it(hbB[it], remB, pq, w1f, w2f, g1p, be1p,
                g2lo, g2hi, be2lo, be2hi, b2lo, b2hi, laLoB, laHiB);
    }

    // pool over the 16 point-columns; lane (g, q==0) writes c = 4g..4g+3
    float a0 = laLoA[0], a1 = laLoA[1], a2 = laHiA[0], a3 = laHiA[1];
    float b0 = laLoB[0], b1 = laLoB[1], b2v_ = laHiB[0], b3 = laHiB[1];
    #pragma unroll
    for (int off = 1; off < 16; off <<= 1) {
        a0 += __shfl_xor(a0, off);  a1 += __shfl_xor(a1, off);
        a2 += __shfl_xor(a2, off);  a3 += __shfl_xor(a3, off);
        b0 += __shfl_xor(b0, off);  b1 += __shfl_xor(b1, off);
        b2v_ += __shfl_xor(b2v_, off);  b3 += __shfl_xor(b3, off);
    }
    if (q == 0) {
        *(float4*)(part + (size_t)uA * C + 4 * g) = make_float4(a0, a1, a2, a3);
        if (hasB)
            *(float4*)(part + (size_t)uB * C + 4 * g) = make_float4(b0, b1, b2v_, b3);
    }
}

// ---------- K3: encoder MLP per batch (unchanged) ----------
__global__ __launch_bounds__(EH) void k_enc(
    const float* __restrict__ part, const int* __restrict__ cnt,
    const float* __restrict__ We1, const float* __restrict__ bb1,
    const float* __restrict__ gg1, const float* __restrict__ bbe1,
    const float* __restrict__ We2, const float* __restrict__ bb2,
    const float* __restrict__ gg2, const float* __restrict__ bbe2,
    float* __restrict__ out)
{
    const int b = blockIdx.x;
    const int t = threadIdx.x;
    __shared__ int sP[64];
    __shared__ float red[8][16];
    __shared__ float cc[C];
    __shared__ float stats[2];
    __shared__ float buf[EH];
    __shared__ float buf2[2 * L];

    if (t < 64) {
        int p = (cnt[t] + 63) >> 6;
        #pragma unroll
        for (int off = 1; off < 64; off <<= 1) {
            const int pv = __shfl_up(p, off);
            if (t >= off) p += pv;
        }
        sP[t] = p;
    }
    __syncthreads();
    const int n = cnt[b];
    const int row0 = (b == 0) ? 0 : sP[b - 1];
    const int rows = sP[b] - row0;

    {
        const int c = t & 15, s = t >> 4;
        float ps = 0.f;
        for (int r = s; r < rows; r += 8)
            ps += part[(size_t)(row0 + r) * C + c];
        red[s][c] = ps;
    }
    __syncthreads();
    if (t < C) {
        float v = 0.f;
        #pragma unroll
        for (int s = 0; s < 8; ++s) v += red[s][t];
        cc[t] = v;
    }
    __syncthreads();
    const float inv = 1.f / fmaxf((float)n, 1.f);

    float v1 = bb1[t];
    #pragma unroll
    for (int c = 0; c < C; ++c)
        v1 = fmaf(cc[c] * inv, We1[c * EH + t], v1);
    buf[t] = v1;
    __syncthreads();
    if (t == 0) {
        float s = 0.f, ss = 0.f;
        for (int j2 = 0; j2 < EH; ++j2) { s += buf[j2]; ss = fmaf(buf[j2], buf[j2], ss); }
        float mn = s * (1.f / EH);
        float vr = fmaxf(ss * (1.f / EH) - mn * mn, 0.f);
        stats[0] = mn; stats[1] = rsqrtf(vr + EPSF);
    }
    __syncthreads();
    float e1 = fmaxf(fmaf((v1 - stats[0]) * stats[1], gg1[t], bbe1[t]), 0.f);
    __syncthreads();
    buf[t] = e1;
    __syncthreads();

    float v2 = 0.f;
    if (t < 2 * L) {
        v2 = bb2[t];
        #pragma unroll
        for (int h = 0; h < EH; ++h)
            v2 = fmaf(buf[h], We2[h * (2 * L) + t], v2);
        buf2[t] = v2;
    }
    __syncthreads();
    if (t == 0) {
        float s = 0.f, ss = 0.f;
        for (int j2 = 0; j2 < 2 * L; ++j2) { s += buf2[j2]; ss = fmaf(buf2[j2], buf2[j2], ss); }
        float mn = s * (1.f / (2 * L));
        float vr = fmaxf(ss * (1.f / (2 * L)) - mn * mn, 0.f);
        stats[0] = mn; stats[1] = rsqrtf(vr + EPSF);
    }
    __syncthreads();
    if (t < 2 * L) {
        float e2 = fmaxf(fmaf((v2 - stats[0]) * stats[1], gg2[t], bbe2[t]), 0.f);
        if (t < L) out[(size_t)b * L + t]                       = e2;  // mu
        else       out[(size_t)B * L + (size_t)b * L + (t - L)] = e2;  // logvar
    }
}

extern "C" void kernel_launch(void* const* d_in, const int* in_sizes, int n_in,
                              void* d_out, int out_size, void* d_ws, size_t ws_size,
                              hipStream_t stream) {
    const float* x    = (const float*)d_in[0];
    const int*   mask = (const int*)d_in[1];
    const float* fe   = (const float*)d_in[2];
    const float* W1   = (const float*)d_in[3];
    const float* b1   = (const float*)d_in[4];
    const float* g1   = (const float*)d_in[5];
    const float* be1  = (const float*)d_in[6];
    const float* W2   = (const float*)d_in[7];
    const float* b2   = (const float*)d_in[8];
    const float* g2   = (const float*)d_in[9];
    const float* be2  = (const float*)d_in[10];
    const float* We1  = (const float*)d_in[11];
    const float* bb1  = (const float*)d_in[12];
    const float* gg1  = (const float*)d_in[13];
    const float* bbe1 = (const float*)d_in[14];
    const float* We2  = (const float*)d_in[15];
    const float* bb2  = (const float*)d_in[16];
    const float* gg2  = (const float*)d_in[17];
    const float* bbe2 = (const float*)d_in[18];
    float* out = (float*)d_out;

    char* wp = (char*)d_ws;
    float* part     = (float*)wp;               wp += (size_t)MAXU * C * 4;
    int*   cnt      = (int*)wp;                 wp += (size_t)B * 4;
    unsigned short* W1T = (unsigned short*)wp;  wp += (size_t)H * 32 * 2;
    unsigned short* W2T = (unsigned short*)wp;  wp += (size_t)C * H * 2;
    unsigned short* febf = (unsigned short*)wp; wp += (size_t)D * C * 2;
    unsigned int*   hxp = (unsigned int*)wp;    wp += (size_t)B * DPAD * 4;
    unsigned short* cd  = (unsigned short*)wp;

    hipLaunchKernelGGL(k_prep, dim3(B + 2 + FB), dim3(1024), 0, stream,
                       mask, x, fe, W1, b1, W2, cnt, cd, hxp, febf, W1T, W2T);
    hipLaunchKernelGGL(k_rows, dim3(NW), dim3(64), 0, stream,
                       cnt, cd, hxp, febf, W1T, W2T, g1, be1, g2, be2, b2, part);
    hipLaunchKernelGGL(k_enc, dim3(B), dim3(EH), 0, stream,
                       part, cnt, We1, bb1, gg1, bbe1, We2, bb2, gg2, bbe2, out);
}

// Round 20
// 47.179 us; speedup vs baseline: 1.1165x; 1.0432x over previous
//
#include <hip/hip_runtime.h>
#include <hip/hip_bf16.h>

#define EPSF 1e-5f

namespace {
constexpr int B = 64, D = 20000, C = 16, H = 64, EH = 128, L = 32;
constexpr int DPAD = ((D + 63) / 64) * 64;      // 20032
constexpr int NB = 1280;                        // 5120 waves; 2 units/wave (best)
constexpr int SSTRIDE = NB * 4;                 // 5120
constexpr int FB = 14;
constexpr int MAXU = B * (DPAD / 64);
}

typedef __attribute__((ext_vector_type(8))) short bf16x8;
typedef __attribute__((ext_vector_type(4))) float f32x4;
typedef __attribute__((ext_vector_type(2))) float f32x2;
typedef __attribute__((ext_vector_type(4))) unsigned int u32x4;

#if defined(__has_builtin)
#if __has_builtin(__builtin_amdgcn_permlane16_swap) && __has_builtin(__builtin_amdgcn_permlane32_swap)
#define HAVE_PL_SWAP 1
#endif
#endif
#ifndef HAVE_PL_SWAP
#define HAVE_PL_SWAP 0
#endif

static __device__ __forceinline__ unsigned short f2bf(float f) {
    __hip_bfloat16 h = __float2bfloat16(f);
    return __builtin_bit_cast(unsigned short, h);
}
static __device__ __forceinline__ unsigned int packbf(float lo, float hi) {
    return ((unsigned int)f2bf(hi) << 16) | (unsigned int)f2bf(lo);
}
static __device__ __forceinline__ unsigned int cvtpk(float lo, float hi) {
    __hip_bfloat162 h2 = __float22bfloat162_rn(make_float2(lo, hi));
    return ((unsigned int)__builtin_bit_cast(unsigned short, h2.y) << 16)
         | (unsigned int)__builtin_bit_cast(unsigned short, h2.x);
}
static __device__ __forceinline__ f32x2 pk_fma(f32x2 a, f32x2 b, f32x2 c) {
    return __builtin_elementwise_fma(a, b, c);
}
static __device__ __forceinline__ f32x2 pk_add(f32x2 a, f32x2 b) { return a + b; }
static __device__ __forceinline__ f32x2 pk_mul(f32x2 a, f32x2 b) { return a * b; }

// VALU-speed cross-lane partner fetch (round-17 polarity, verified passing)
static __device__ __forceinline__ float xadd16(float v) {
#if HAVE_PL_SWAP
    const int lane = threadIdx.x & 63;
    unsigned a = __builtin_bit_cast(unsigned, v);
    auto r = __builtin_amdgcn_permlane16_swap(a, a, false, false);
    unsigned p = (lane & 16) ? r[0] : r[1];
    return v + __builtin_bit_cast(float, p);
#else
    return v + __shfl_xor(v, 16);
#endif
}
static __device__ __forceinline__ float xadd32(float v) {
#if HAVE_PL_SWAP
    const int lane = threadIdx.x & 63;
    unsigned a = __builtin_bit_cast(unsigned, v);
    auto r = __builtin_amdgcn_permlane32_swap(a, a, false, false);
    unsigned p = (lane & 32) ? r[0] : r[1];
    return v + __builtin_bit_cast(float, p);
#else
    return v + __shfl_xor(v, 32);
#endif
}

// ---------- K1: single-pass compaction + prep (known-good) ----------
__global__ __launch_bounds__(1024) void k_prep(
    const int* __restrict__ mask, const float* __restrict__ x,
    const float* __restrict__ fe,
    const float* __restrict__ W1, const float* __restrict__ b1,
    const float* __restrict__ W2,
    int* __restrict__ cnt,
    unsigned short* __restrict__ cd, unsigned int* __restrict__ hxp,
    unsigned short* __restrict__ febf,
    unsigned short* __restrict__ W1T, unsigned short* __restrict__ W2T)
{
    const int t = threadIdx.x;
    if (blockIdx.x < B) {
        const int b = blockIdx.x;
        const size_t bD = (size_t)b * D;
        const size_t bP = (size_t)b * DPAD;
        constexpr int NIT = (D + 1023) / 1024;   // 20
        int   mv[NIT];
        float xv[NIT];
        #pragma unroll
        for (int it = 0; it < NIT; ++it) {
            const int d = it * 1024 + t;
            const bool in = d < D;
            mv[it] = in ? mask[bD + d] : 0;
            xv[it] = in ? x[bD + d] : 0.f;
        }
        int cl = 0;
        #pragma unroll
        for (int it = 0; it < NIT; ++it) cl += (mv[it] != 0) ? 1 : 0;

        const int lane = t & 63, wid = t >> 6;
        int inc = cl;
        #pragma unroll
        for (int off = 1; off < 64; off <<= 1) {
            const int v = __shfl_up(inc, off);
            if (lane >= off) inc += v;
        }
        __shared__ int ls[16];
        if (lane == 63) ls[wid] = inc;
        __syncthreads();
        int wbase = 0, tot = 0;
        #pragma unroll
        for (int k = 0; k < 16; ++k) {
            const int v = ls[k];
            tot += v;
            if (k < wid) wbase += v;
        }
        int pos = wbase + (inc - cl);

        #pragma unroll
        for (int it = 0; it < NIT; ++it) {
            if (mv[it]) {
                cd[bP + pos]  = (unsigned short)(it * 1024 + t);
                hxp[bP + pos] = packbf(xv[it], 1.0f);
                ++pos;
            }
        }
        const int padend = (tot + 63) & ~63;
        for (int i = tot + t; i < padend; i += 1024) {
            cd[bP + i] = 0;
            hxp[bP + i] = 0u;
        }
        if (t == 0) cnt[b] = tot;
    } else if (blockIdx.x == B) {
        // W1T permuted row->h so layer1 D-layout == layer2 B-layout
        for (int e = t; e < H * 32; e += 1024) {
            const int rIdx = e >> 5, kk = e & 31;
            const int m = rIdx >> 4, rho = rIdx & 15;
            const int h = 32 * (m >> 1) + 8 * (rho >> 2) + 4 * (m & 1) + (rho & 3);
            float v = 0.f;
            if (kk < 16)       v = W1[(kk + 1) * H + h];
            else if (kk == 16) v = W1[h];
            else if (kk == 17) v = b1[h];
            W1T[e] = f2bf(v);
        }
    } else if (blockIdx.x == B + 1) {
        for (int e = t; e < C * H; e += 1024) {
            const int c0 = e >> 6, hh = e & 63;
            W2T[e] = f2bf(W2[hh * C + c0]);
        }
    } else {
        const int pb = blockIdx.x - (B + 2);
        for (int u = pb * 1024 + t; u < (D * C) / 8; u += FB * 1024) {
            const float4 f0 = *(const float4*)(fe + (size_t)u * 8);
            const float4 f1 = *(const float4*)(fe + (size_t)u * 8 + 4);
            uint4 pk;
            pk.x = packbf(f0.x, f0.y); pk.y = packbf(f0.z, f0.w);
            pk.z = packbf(f1.x, f1.y); pk.w = packbf(f1.z, f1.w);
            *(uint4*)(febf + (size_t)u * 8) = pk;
        }
    }
}

// ---- per-iteration unit body (round-17, passing) ----
static __device__ __forceinline__ void unit_it(
    const bf16x8& hbv, int rem, int pq,
    const bf16x8 (&w1f)[4], const bf16x8 (&w2f)[2],
    const f32x2 (&g1p)[4][2], const f32x2 (&be1p)[4][2],
    const f32x2& g2lo, const f32x2& g2hi,
    const f32x2& be2lo, const f32x2& be2hi,
    const f32x2& b2lo, const f32x2& b2hi,
    f32x2& laccLo, f32x2& laccHi)
{
    const f32x4 z = {0.f, 0.f, 0.f, 0.f};
    f32x4 t1a[4];
    #pragma unroll
    for (int m = 0; m < 4; ++m)
        t1a[m] = __builtin_amdgcn_mfma_f32_16x16x32_bf16(w1f[m], hbv, z, 0, 0, 0);

    f32x2 sp = {0.f, 0.f}, qp = {0.f, 0.f};
    f32x2 tl[4], th[4];
    #pragma unroll
    for (int m = 0; m < 4; ++m) {
        tl[m] = __builtin_shufflevector(t1a[m], t1a[m], 0, 1);
        th[m] = __builtin_shufflevector(t1a[m], t1a[m], 2, 3);
        sp = pk_add(sp, pk_add(tl[m], th[m]));
        qp = pk_fma(tl[m], tl[m], pk_fma(th[m], th[m], qp));
    }
    float s  = sp[0] + sp[1];
    float sq = qp[0] + qp[1];
    s = xadd16(s);  sq = xadd16(sq);
    s = xadd32(s);  sq = xadd32(sq);
    const float mean1 = s * (1.f / H);
    const float var1  = fmaxf(sq * (1.f / H) - mean1 * mean1, 0.f);
    const float rstd1 = rsqrtf(var1 + EPSF);

    const f32x2 rr2 = {rstd1, rstd1};
    const f32x2 nm2 = {-mean1, -mean1};
    unsigned int pw[8];
    #pragma unroll
    for (int m = 0; m < 4; ++m) {
        const f32x2 sgl = pk_mul(g1p[m][0], rr2);
        const f32x2 sgh = pk_mul(g1p[m][1], rr2);
        const f32x2 obl = pk_fma(sgl, nm2, be1p[m][0]);
        const f32x2 obh = pk_fma(sgh, nm2, be1p[m][1]);
        const f32x2 yl = pk_fma(tl[m], sgl, obl);
        const f32x2 yh = pk_fma(th[m], sgh, obh);
        pw[2 * m]     = cvtpk(fmaxf(yl[0], 0.f), fmaxf(yl[1], 0.f));
        pw[2 * m + 1] = cvtpk(fmaxf(yh[0], 0.f), fmaxf(yh[1], 0.f));
    }
    const u32x4 r0 = {pw[0], pw[1], pw[2], pw[3]};
    const u32x4 r1 = {pw[4], pw[5], pw[6], pw[7]};
    const bf16x8 rb0 = __builtin_bit_cast(bf16x8, r0);
    const bf16x8 rb1 = __builtin_bit_cast(bf16x8, r1);

    f32x4 a2 = __builtin_amdgcn_mfma_f32_16x16x32_bf16(w2f[0], rb0, z, 0, 0, 0);
    a2 = __builtin_amdgcn_mfma_f32_16x16x32_bf16(w2f[1], rb1, a2, 0, 0, 0);

    f32x2 alo = __builtin_shufflevector(a2, a2, 0, 1);
    f32x2 ahi = __builtin_shufflevector(a2, a2, 2, 3);
    alo = pk_add(alo, b2lo);
    ahi = pk_add(ahi, b2hi);
    const f32x2 sp2 = pk_add(alo, ahi);
    const f32x2 zz = {0.f, 0.f};
    const f32x2 qp2 = pk_fma(alo, alo, pk_fma(ahi, ahi, zz));
    float s2 = sp2[0] + sp2[1];
    float q2 = qp2[0] + qp2[1];
    s2 = xadd16(s2);  q2 = xadd16(q2);
    s2 = xadd32(s2);  q2 = xadd32(q2);
    const float mean2 = s2 * (1.f / C);
    const float var2  = fmaxf(q2 * (1.f / C) - mean2 * mean2, 0.f);
    const float rstd2 = rsqrtf(var2 + EPSF);

    const f32x2 rrb = {rstd2, rstd2};
    const f32x2 nmb = {-mean2, -mean2};
    const f32x2 sg2l = pk_mul(g2lo, rrb);
    const f32x2 sg2h = pk_mul(g2hi, rrb);
    const f32x2 ob2l = pk_fma(sg2l, nmb, be2lo);
    const f32x2 ob2h = pk_fma(sg2h, nmb, be2hi);
    const f32x2 y2l = pk_fma(alo, sg2l, ob2l);
    const f32x2 y2h = pk_fma(ahi, sg2h, ob2h);
    const float vm = (pq < rem) ? 1.f : 0.f;
    const f32x2 vm2 = {vm, vm};
    const f32x2 rl = {fmaxf(y2l[0], 0.f), fmaxf(y2l[1], 0.f)};
    const f32x2 rh = {fmaxf(y2h[0], 0.f), fmaxf(y2h[1], 0.f)};
    laccLo = pk_fma(rl, vm2, laccLo);
    laccHi = pk_fma(rh, vm2, laccHi);
}

// ---------- K2: LDS-free MFMA pointnet, 2 units per wave (best config) ----------
__global__ __launch_bounds__(256, 2) void k_rows(
    const int* __restrict__ cnt,
    const unsigned short* __restrict__ cd, const unsigned int* __restrict__ hxp,
    const unsigned short* __restrict__ febf,
    const unsigned short* __restrict__ W1T, const unsigned short* __restrict__ W2T,
    const float* __restrict__ g1, const float* __restrict__ be1,
    const float* __restrict__ g2, const float* __restrict__ be2,
    const float* __restrict__ b2,
    float* __restrict__ part)      // [MAXU][C]
{
    const int tid = threadIdx.x;
    const int w = tid >> 6, lane = tid & 63;
    const int g = lane >> 4, q = lane & 15;

    const int cv  = cnt[lane];
    const int nuv = (cv + 63) >> 6;
    int Pi = nuv;
    #pragma unroll
    for (int off = 1; off < 64; off <<= 1) {
        const int pv = __shfl_up(Pi, off);
        if (lane >= off) Pi += pv;
    }
    const int T = __shfl(Pi, 63);

    const int uA = blockIdx.x * 4 + w;
    if (uA >= T) return;
    const bool hasB = (uA + SSTRIDE) < T;
    const int uB = hasB ? uA + SSTRIDE : uA;

    bf16x8 w1f[4];
    #pragma unroll
    for (int m = 0; m < 4; ++m)
        w1f[m] = *(const bf16x8*)(W1T + (16 * m + q) * 32 + 8 * g);
    bf16x8 w2f[2];
    #pragma unroll
    for (int ks = 0; ks < 2; ++ks)
        w2f[ks] = *(const bf16x8*)(W2T + q * 64 + 32 * ks + 8 * g);

    f32x2 g1p[4][2], be1p[4][2];
    #pragma unroll
    for (int m = 0; m < 4; ++m) {
        const int h0 = 32 * (m >> 1) + 8 * g + 4 * (m & 1);
        g1p[m][0]  = *(const f32x2*)(g1  + h0);
        g1p[m][1]  = *(const f32x2*)(g1  + h0 + 2);
        be1p[m][0] = *(const f32x2*)(be1 + h0);
        be1p[m][1] = *(const f32x2*)(be1 + h0 + 2);
    }
    const f32x2 g2lo  = *(const f32x2*)(g2  + 4 * g);
    const f32x2 g2hi  = *(const f32x2*)(g2  + 4 * g + 2);
    const f32x2 be2lo = *(const f32x2*)(be2 + 4 * g);
    const f32x2 be2hi = *(const f32x2*)(be2 + 4 * g + 2);
    const f32x2 b2lo  = *(const f32x2*)(b2  + 4 * g);
    const f32x2 b2hi  = *(const f32x2*)(b2  + 4 * g + 2);

    // resolve both units: unit -> (batch row base, remaining valid points)
    size_t rowbA, rowbB;
    int remA, remB;
    {
        const unsigned long long blA = __ballot(Pi <= uA);
        const int bA   = __popcll(blA);
        const int PbA  = __shfl(Pi, bA);
        const int nubA = __shfl(nuv, bA);
        const int nA   = __shfl(cv, bA);
        const int baseA = (uA - (PbA - nubA)) * 64;
        rowbA = (size_t)bA * DPAD + baseA;
        remA  = nA - baseA;
        const unsigned long long blB = __ballot(Pi <= uB);
        const int bB   = __popcll(blB);
        const int PbB  = __shfl(Pi, bB);
        const int nubB = __shfl(nuv, bB);
        const int nB   = __shfl(cv, bB);
        const int baseB = (uB - (PbB - nubB)) * 64;
        rowbB = (size_t)bB * DPAD + baseB;
        remB  = nB - baseB;
    }

    const int dvA = (int)cd[rowbA + lane];
    const int dvB = (int)cd[rowbB + lane];

    bf16x8 hbA[4], hbB[4];
    #pragma unroll
    for (int it = 0; it < 4; ++it) {
        const int p = (it << 4) + q;
        {
            const int dd = __shfl(dvA, p);
            bf16x8 hv = {0, 0, 0, 0, 0, 0, 0, 0};
            if (g < 2) {
                hv = *(const bf16x8*)(febf + (size_t)dd * 16 + 8 * g);
            } else if (g == 2) {
                const unsigned int xv = hxp[rowbA + p];
                const u32x4 tmp = {xv, 0u, 0u, 0u};
                hv = __builtin_bit_cast(bf16x8, tmp);
            }
            hbA[it] = hv;
        }
        {
            const int dd = __shfl(dvB, p);
            bf16x8 hv = {0, 0, 0, 0, 0, 0, 0, 0};
            if (g < 2) {
                hv = *(const bf16x8*)(febf + (size_t)dd * 16 + 8 * g);
            } else if (g == 2) {
                const unsigned int xv = hxp[rowbB + p];
                const u32x4 tmp = {xv, 0u, 0u, 0u};
                hv = __builtin_bit_cast(bf16x8, tmp);
            }
            hbB[it] = hv;
        }
    }

    f32x2 laLoA = {0.f, 0.f}, laHiA = {0.f, 0.f};
    f32x2 laLoB = {0.f, 0.f}, laHiB = {0.f, 0.f};
    #pragma unroll
    for (int it = 0; it < 4; ++it) {
        const int pq = (it << 4) + q;
        unit_it(hbA[it], remA, pq, w1f, w2f, g1p, be1p,
                g2lo, g2hi, be2lo, be2hi, b2lo, b2hi, laLoA, laHiA);
        unit_it(hbB[it], remB, pq, w1f, w2f, g1p, be1p,
                g2lo, g2hi, be2lo, be2hi, b2lo, b2hi, laLoB, laHiB);
    }

    // pool over the 16 point-columns; lane (g, q==0) writes c = 4g..4g+3
    float a0 = laLoA[0], a1 = laLoA[1], a2 = laHiA[0], a3 = laHiA[1];
    float b0 = laLoB[0], b1 = laLoB[1], b2v_ = laHiB[0], b3 = laHiB[1];
    #pragma unroll
    for (int off = 1; off < 16; off <<= 1) {
        a0 += __shfl_xor(a0, off);  a1 += __shfl_xor(a1, off);
        a2 += __shfl_xor(a2, off);  a3 += __shfl_xor(a3, off);
        b0 += __shfl_xor(b0, off);  b1 += __shfl_xor(b1, off);
        b2v_ += __shfl_xor(b2v_, off);  b3 += __shfl_xor(b3, off);
    }
    if (q == 0) {
        *(float4*)(part + (size_t)uA * C + 4 * g) = make_float4(a0, a1, a2, a3);
        if (hasB)
            *(float4*)(part + (size_t)uB * C + 4 * g) = make_float4(b0, b1, b2v_, b3);
    }
}

// ---------- K3: encoder MLP per batch — wave-parallel LN reductions ----------
__global__ __launch_bounds__(EH) void k_enc(
    const float* __restrict__ part, const int* __restrict__ cnt,
    const float* __restrict__ We1, const float* __restrict__ bb1,
    const float* __restrict__ gg1, const float* __restrict__ bbe1,
    const float* __restrict__ We2, const float* __restrict__ bb2,
    const float* __restrict__ gg2, const float* __restrict__ bbe2,
    float* __restrict__ out)
{
    const int b = blockIdx.x;
    const int t = threadIdx.x;
    const int lane = t & 63, wid = t >> 6;
    __shared__ int sP[64];
    __shared__ float red[8][16];
    __shared__ float cc[C];
    __shared__ float wred[2][2];
    __shared__ float buf[EH];

    if (t < 64) {
        int p = (cnt[t] + 63) >> 6;
        #pragma unroll
        for (int off = 1; off < 64; off <<= 1) {
            const int pv = __shfl_up(p, off);
            if (t >= off) p += pv;
        }
        sP[t] = p;
    }
    __syncthreads();
    const int n = cnt[b];
    const int row0 = (b == 0) ? 0 : sP[b - 1];
    const int rows = sP[b] - row0;

    {
        const int c = t & 15, s = t >> 4;
        float ps = 0.f;
        for (int r = s; r < rows; r += 8)
            ps += part[(size_t)(row0 + r) * C + c];
        red[s][c] = ps;
    }
    __syncthreads();
    if (t < C) {
        float v = 0.f;
        #pragma unroll
        for (int s = 0; s < 8; ++s) v += red[s][t];
        cc[t] = v;
    }
    __syncthreads();
    const float inv = 1.f / fmaxf((float)n, 1.f);

    // e1 = c @ We1 + bb1 (thread t owns column t of EH=128)
    float v1 = bb1[t];
    #pragma unroll
    for (int c = 0; c < C; ++c)
        v1 = fmaf(cc[c] * inv, We1[c * EH + t], v1);

    // LN over EH via two-wave parallel reduce
    float sv = v1, qv = v1 * v1;
    #pragma unroll
    for (int off = 1; off < 64; off <<= 1) {
        sv += __shfl_xor(sv, off);
        qv += __shfl_xor(qv, off);
    }
    if (lane == 0) { wred[wid][0] = sv; wred[wid][1] = qv; }
    __syncthreads();
    const float S1 = wred[0][0] + wred[1][0];
    const float Q1 = wred[0][1] + wred[1][1];
    const float mn1 = S1 * (1.f / EH);
    const float vr1 = fmaxf(Q1 * (1.f / EH) - mn1 * mn1, 0.f);
    const float rs1 = rsqrtf(vr1 + EPSF);
    const float e1 = fmaxf(fmaf((v1 - mn1) * rs1, gg1[t], bbe1[t]), 0.f);
    buf[t] = e1;
    __syncthreads();

    // e2 = e1 @ We2 + bb2 (wave 0 exactly covers 2L=64 outputs)
    if (wid == 0) {
        float v2 = bb2[t];
        #pragma unroll
        for (int h = 0; h < EH; ++h)
            v2 = fmaf(buf[h], We2[h * (2 * L) + t], v2);

        // LN over 2L=64 via single-wave reduce
        float sv2 = v2, qv2 = v2 * v2;
        #pragma unroll
        for (int off = 1; off < 64; off <<= 1) {
            sv2 += __shfl_xor(sv2, off);
            qv2 += __shfl_xor(qv2, off);
        }
        const float mn2 = sv2 * (1.f / (2 * L));
        const float vr2 = fmaxf(qv2 * (1.f / (2 * L)) - mn2 * mn2, 0.f);
        const float rs2 = rsqrtf(vr2 + EPSF);
        const float e2 = fmaxf(fmaf((v2 - mn2) * rs2, gg2[t], bbe2[t]), 0.f);
        if (t < L) out[(size_t)b * L + t]                       = e2;  // mu
        else       out[(size_t)B * L + (size_t)b * L + (t - L)] = e2;  // logvar
    }
}

extern "C" void kernel_launch(void* const* d_in, const int* in_sizes, int n_in,
                              void* d_out, int out_size, void* d_ws, size_t ws_size,
                              hipStream_t stream) {
    const float* x    = (const float*)d_in[0];
    const int*   mask = (const int*)d_in[1];
    const float* fe   = (const float*)d_in[2];
    const float* W1   = (const float*)d_in[3];
    const float* b1   = (const float*)d_in[4];
    const float* g1   = (const float*)d_in[5];
    const float* be1  = (const float*)d_in[6];
    const float* W2   = (const float*)d_in[7];
    const float* b2   = (const float*)d_in[8];
    const float* g2   = (const float*)d_in[9];
    const float* be2  = (const float*)d_in[10];
    const float* We1  = (const float*)d_in[11];
    const float* bb1  = (const float*)d_in[12];
    const float* gg1  = (const float*)d_in[13];
    const float* bbe1 = (const float*)d_in[14];
    const float* We2  = (const float*)d_in[15];
    const float* bb2  = (const float*)d_in[16];
    const float* gg2  = (const float*)d_in[17];
    const float* bbe2 = (const float*)d_in[18];
    float* out = (float*)d_out;

    char* wp = (char*)d_ws;
    float* part     = (float*)wp;               wp += (size_t)MAXU * C * 4;
    int*   cnt      = (int*)wp;                 wp += (size_t)B * 4;
    unsigned short* W1T = (unsigned short*)wp;  wp += (size_t)H * 32 * 2;
    unsigned short* W2T = (unsigned short*)wp;  wp += (size_t)C * H * 2;
    unsigned short* febf = (unsigned short*)wp; wp += (size_t)D * C * 2;
    unsigned int*   hxp = (unsigned int*)wp;    wp += (size_t)B * DPAD * 4;
    unsigned short* cd  = (unsigned short*)wp;

    hipLaunchKernelGGL(k_prep, dim3(B + 2 + FB), dim3(1024), 0, stream,
                       mask, x, fe, W1, b1, W2, cnt, cd, hxp, febf, W1T, W2T);
    hipLaunchKernelGGL(k_rows, dim3(NB), dim3(256), 0, stream,
                       cnt, cd, hxp, febf, W1T, W2T, g1, be1, g2, be2, b2, part);
    hipLaunchKernelGGL(k_enc, dim3(B), dim3(EH), 0, stream,
                       part, cnt, We1, bb1, gg1, bbe1, We2, bb2, gg2, bbe2, out);
}